// Round 7
// baseline (666.164 us; speedup 1.0000x reference)
//
#include <hip/hip_runtime.h>

typedef __attribute__((ext_vector_type(4))) float f32x4;
typedef __attribute__((ext_vector_type(8))) short bf16x8;

constexpr int TOK = 8192;   // B*S
constexpr int DD  = 1024;   // D
constexpr int HH  = 2048;   // H
constexpr int NE  = 8;      // experts

// ---- workspace layout (bytes) ----
// 0      topk_idx   int[16384]        [0, 65536)
// 65536  topk_prob  f32[16384]        [65536, 131072)
// 131072 counts     int[8]; 131104 cursor int[8]; 131136 offsets int[9]
// 131264 token_list int[16384]        [131264, 196800)
// 196800 slot       int[16384]        [196800, 262336)
// 524288            x_bf   bf16[8192*1024]      (16.8 MB)  [dead after gateup]
// 524288            y      f32[16384*1024]      (67.1 MB)  [overlays x_bf/gw_bf/uw_bf]
// 17301504          gw_bf  bf16[8*2048*1024]    (33.6 MB)  [dead after gateup]
// 50855936          uw_bf  bf16[8*2048*1024]    (33.6 MB)  [dead after gateup]
// 84410368          dw_bf  bf16[8*1024*2048]    (33.6 MB)
// 117964800         act    bf16[16384*2048]     (67.1 MB)
// total need: 185,073,664 B

__device__ __forceinline__ unsigned short f2bf(float f) {
    union { float f; unsigned u; } v; v.f = f;
    unsigned r = v.u + 0x7fffu + ((v.u >> 16) & 1u);   // RNE
    return (unsigned short)(r >> 16);
}

__device__ __forceinline__ void gl2lds16(const void* g, void* l) {
    __builtin_amdgcn_global_load_lds(
        (const __attribute__((address_space(1))) unsigned int*)g,
        (__attribute__((address_space(3))) unsigned int*)l, 16, 0, 0);
}

// ------------- router: logits, top-2, probs; also emits x in bf16 -------------
__global__ __launch_bounds__(256) void k_router(
    const float* __restrict__ x, const float* __restrict__ rw,
    int* __restrict__ topk_idx, float* __restrict__ topk_prob,
    int* __restrict__ counts, unsigned short* __restrict__ x_bf)
{
    int wave = threadIdx.x >> 6;
    int lane = threadIdx.x & 63;
    int t = blockIdx.x * 4 + wave;

    const float4* xr = (const float4*)(x + (size_t)t * DD);
    float4 xv[4];
#pragma unroll
    for (int i = 0; i < 4; i++) xv[i] = xr[lane + 64 * i];

#pragma unroll
    for (int i = 0; i < 4; i++) {
        ushort4 u4 = make_ushort4(f2bf(xv[i].x), f2bf(xv[i].y),
                                  f2bf(xv[i].z), f2bf(xv[i].w));
        *(ushort4*)(x_bf + (size_t)t * DD + (lane + 64 * i) * 4) = u4;
    }

    float acc[NE];
#pragma unroll
    for (int e = 0; e < NE; e++) {
        const float4* wr = (const float4*)(rw + (size_t)e * DD);
        float s = 0.f;
#pragma unroll
        for (int i = 0; i < 4; i++) {
            float4 w = wr[lane + 64 * i];
            s += xv[i].x * w.x + xv[i].y * w.y + xv[i].z * w.z + xv[i].w * w.w;
        }
        acc[e] = s;
    }
#pragma unroll
    for (int e = 0; e < NE; e++) {
        float s = acc[e];
        for (int m = 32; m >= 1; m >>= 1) s += __shfl_xor(s, m);
        acc[e] = s;
    }
    if (lane == 0) {
        int b0 = 0; float l0 = acc[0];
#pragma unroll
        for (int e = 1; e < NE; e++) if (acc[e] > l0) { l0 = acc[e]; b0 = e; }
        int b1 = -1; float l1 = -3.0e38f;
#pragma unroll
        for (int e = 0; e < NE; e++) if (e != b0 && acc[e] > l1) { l1 = acc[e]; b1 = e; }
        float p0 = 1.f / (1.f + __expf(l1 - l0));
        float p1 = 1.f - p0;
        topk_idx[t * 2 + 0] = b0;  topk_idx[t * 2 + 1] = b1;
        topk_prob[t * 2 + 0] = p0; topk_prob[t * 2 + 1] = p1;
        atomicAdd(&counts[b0], 1);
        atomicAdd(&counts[b1], 1);
    }
}

__global__ void k_scan(const int* __restrict__ counts, int* __restrict__ offsets) {
    if (threadIdx.x == 0) {
        int s = 0;
        for (int e = 0; e < NE; e++) { offsets[e] = s; s += counts[e]; }
        offsets[NE] = s;
    }
}

__global__ __launch_bounds__(256) void k_scatter(
    const int* __restrict__ topk_idx,
    const int* __restrict__ offsets, int* __restrict__ cursor,
    int* __restrict__ token_list, int* __restrict__ slot)
{
    int t = blockIdx.x * 256 + threadIdx.x;
#pragma unroll
    for (int k = 0; k < 2; k++) {
        int e = topk_idx[t * 2 + k];
        int pos = atomicAdd(&cursor[e], 1);
        token_list[offsets[e] + pos] = t;
        slot[t * 2 + k] = offsets[e] + pos;
    }
}

// ---------------- merged f32 -> bf16 bulk convert of gw/uw/dw ----------------
__global__ __launch_bounds__(256) void k_cvt_all(
    const float* __restrict__ gw, const float* __restrict__ uw,
    const float* __restrict__ dw,
    unsigned short* __restrict__ gwb, unsigned short* __restrict__ uwb,
    unsigned short* __restrict__ dwb)
{
    constexpr int SEG = NE * HH * DD / 8;
    int i = blockIdx.x * blockDim.x + threadIdx.x;
    int stride = gridDim.x * blockDim.x;
    for (; i < 3 * SEG; i += stride) {
        const float* in; unsigned short* out; int j = i;
        if (j < SEG)            { in = gw; out = gwb; }
        else if (j < 2 * SEG)   { in = uw; out = uwb; j -= SEG; }
        else                    { in = dw; out = dwb; j -= 2 * SEG; }
        const float4* p = (const float4*)(in + (size_t)j * 8);
        float4 a = p[0], b = p[1];
        uint4 v;
        v.x = (unsigned)f2bf(a.x) | ((unsigned)f2bf(a.y) << 16);
        v.y = (unsigned)f2bf(a.z) | ((unsigned)f2bf(a.w) << 16);
        v.z = (unsigned)f2bf(b.x) | ((unsigned)f2bf(b.y) << 16);
        v.w = (unsigned)f2bf(b.z) | ((unsigned)f2bf(b.w) << 16);
        *(uint4*)(out + (size_t)j * 8) = v;
    }
}

// ==================== 256x256 4-phase fine-interleaved GEMMs ====================
// Tile 256x256, BK=64, 8 waves (2m x 4n), wave = 128x64. LDS 2 x 64 KB dbuf.
// Per K-tile: 4 phases (mq,kk): {ds_read 8|4 x b128 ; 2 x gl2lds of tile t+1 ;
// s_barrier ; setprio(1) ; 16 MFMA ; setprio(0) ; [vmcnt(0) at ph3] ; s_barrier}.
// Stages of tile t+1 land in buf^1 (free since tile t-1's end barrier); the
// phase-3 vmcnt(0)+barrier guarantees landing before tile t+1's reads.

#define PHASE(mq, kk, ph, TILE, STAGE_OK)  do {                                  \
    const int kb_ = (kk) * 64 + hi16;                                            \
    if ((mq) == 0) {                                                             \
        _Pragma("unroll") for (int nj = 0; nj < 4; nj++) {                       \
            int br_ = wn * 64 + nj * 16 + l15;                                   \
            bfr[nj] = *(const bf16x8*)(Lb + br_ * 128 + (kb_ ^ ((br_ & 7) << 4))); } } \
    bf16x8 af[4];                                                                \
    _Pragma("unroll") for (int q = 0; q < 4; q++) {                              \
        int row_ = wm * 128 + ((mq) * 4 + q) * 16 + l15;                         \
        af[q] = *(const bf16x8*)(La + row_ * 128 + (kb_ ^ ((row_ & 7) << 4))); } \
    if (STAGE_OK) {                                                              \
        gl2lds16(src[2*(ph)]   + ((TILE)+1)*128, nb + wvoff + 2048*(ph));        \
        gl2lds16(src[2*(ph)+1] + ((TILE)+1)*128, nb + wvoff + 2048*(ph) + 1024); } \
    __builtin_amdgcn_s_barrier();                                                \
    asm volatile("" ::: "memory");                                               \
    __builtin_amdgcn_s_setprio(1);                                               \
    _Pragma("unroll") for (int q = 0; q < 4; q++)                                \
        _Pragma("unroll") for (int nj = 0; nj < 4; nj++)                         \
            acc[(mq)*4+q][nj] = __builtin_amdgcn_mfma_f32_16x16x32_bf16(         \
                af[q], bfr[nj], acc[(mq)*4+q][nj], 0, 0, 0);                     \
    __builtin_amdgcn_s_setprio(0);                                               \
    if ((ph) == 3) asm volatile("s_waitcnt vmcnt(0)" ::: "memory");              \
    __builtin_amdgcn_s_barrier();                                                \
    asm volatile("" ::: "memory");                                               \
} while (0)

// gateup: A = gathered tokens (256), B-rows 256 = per-wn {32 gate + 32 up} cols.
__global__ __launch_bounds__(512) void k_gateup_v4(
    const unsigned short* __restrict__ xb,
    const unsigned short* __restrict__ gwb,
    const unsigned short* __restrict__ uwb,
    const int* __restrict__ offsets,
    const int* __restrict__ token_list,
    unsigned short* __restrict__ act)
{
    extern __shared__ char lds[];   // 2 x 65536: per buf A 32K | B 32K

    const int bid = blockIdx.x;
    const int e   = bid & 7;           // expert -> XCD
    const int s   = bid >> 3;
    const int n   = s >> 6;            // n-outer (weight panel L2-resident)
    const int m   = s & 63;            // m-inner
    const int off = offsets[e];
    const int n_e = offsets[e + 1] - off;
    const int m0  = m * 256;
    if (m0 >= n_e) return;
    const int n0g = n * 128;           // gate/up col base (128 H-cols per block)

    const int tid = threadIdx.x, lane = tid & 63, wid = tid >> 6;
    const int wm = wid >> 2, wn = wid & 3;            // 2m x 4n
    const int l8 = lane >> 3, l15 = lane & 15, hi16 = (lane >> 4) * 16;
    const int colb = ((lane & 7) * 16) ^ (l8 << 4);   // pre-swizzled src col byte
    const unsigned wvoff = wid * 8192u;               // this wave's 8 chunk bytes

    // 64 chunks (1 KB = 8 rows x 128 B): A: 0..31, B: 32..63. Wave stages 8.
    const char* src[8];
#pragma unroll
    for (int i = 0; i < 8; i++) {
        int c = wid * 8 + i;
        if (c < 32) {
            int rg = m0 + c * 8 + l8; if (rg > n_e - 1) rg = n_e - 1;
            int tok = token_list[off + rg];
            src[i] = (const char*)xb + (size_t)tok * (DD * 2) + colb;
        } else {
            int tr = (c - 32) * 8 + l8;           // B-row 0..255
            int grp = tr >> 6, j = tr & 63;
            const unsigned short* W = (j < 32) ? gwb : uwb;
            int wcol = n0g + grp * 32 + (j & 31);
            src[i] = (const char*)W + ((size_t)e * HH + wcol) * (DD * 2) + colb;
        }
    }

    f32x4 acc[8][4] = {};

    // prologue: stage tile 0 into buf 0
#pragma unroll
    for (int i = 0; i < 8; i++) gl2lds16(src[i], lds + wvoff + i * 1024u);
    asm volatile("s_waitcnt vmcnt(0)" ::: "memory");
    __builtin_amdgcn_s_barrier();
    asm volatile("" ::: "memory");

    constexpr int NT = (DD * 2) / 128;   // 16 K-tiles
    for (int t = 0; t < NT - 1; ++t) {
        const char* La = lds + (t & 1) * 65536u;
        const char* Lb = La + 32768;
        char* nb = lds + ((t + 1) & 1) * 65536u;
        bf16x8 bfr[4];
        PHASE(0, 0, 0, t, 1);
        PHASE(1, 0, 1, t, 1);
        PHASE(0, 1, 2, t, 1);
        PHASE(1, 1, 3, t, 1);
    }
    {   // final tile: no staging
        const int t = NT - 1;
        const char* La = lds + (t & 1) * 65536u;
        const char* Lb = La + 32768;
        char* nb = lds;  (void)nb;
        bf16x8 bfr[4];
        PHASE(0, 0, 0, t, 0);
        PHASE(1, 0, 1, t, 0);
        PHASE(0, 1, 2, t, 0);
        PHASE(1, 1, 3, t, 0);
    }

    // epilogue: silu(g)*u -> act bf16   (acc nj 0,1 = gate; 2,3 = up)
#pragma unroll
    for (int mi = 0; mi < 8; mi++) {
#pragma unroll
        for (int r2 = 0; r2 < 4; r2++) {
            int row = wm * 128 + mi * 16 + (lane >> 4) * 4 + r2;
            int rg = m0 + row;
            if (rg >= n_e) continue;
            size_t rowbase = (size_t)(off + rg) * HH + n0g + wn * 32;
#pragma unroll
            for (int nj = 0; nj < 2; nj++) {
                float gg = acc[mi][nj][r2];
                float uu = acc[mi][nj + 2][r2];
                float sv = gg / (1.f + __expf(-gg)) * uu;
                act[rowbase + nj * 16 + l15] = f2bf(sv);
            }
        }
    }
}

// down: A = act rows (contiguous grouped), B = dw (256 D-cols), K=2048 -> y f32.
__global__ __launch_bounds__(512) void k_down_v4(
    const unsigned short* __restrict__ act,
    const unsigned short* __restrict__ dwb,
    const int* __restrict__ offsets,
    float* __restrict__ y)
{
    extern __shared__ char lds[];   // 2 x 65536

    const int bid = blockIdx.x;
    const int e   = bid & 7;
    const int s   = bid >> 3;
    const int n   = s >> 6;            // 4 n-slices, n-outer
    const int m   = s & 63;
    const int off = offsets[e];
    const int n_e = offsets[e + 1] - off;
    const int m0  = m * 256;
    if (m0 >= n_e) return;
    const int n0  = n * 256;           // D col base

    const int tid = threadIdx.x, lane = tid & 63, wid = tid >> 6;
    const int wm = wid >> 2, wn = wid & 3;
    const int l8 = lane >> 3, l15 = lane & 15, hi16 = (lane >> 4) * 16;
    const int colb = ((lane & 7) * 16) ^ (l8 << 4);
    const unsigned wvoff = wid * 8192u;

    const char* src[8];
#pragma unroll
    for (int i = 0; i < 8; i++) {
        int c = wid * 8 + i;
        if (c < 32) {
            int rg = m0 + c * 8 + l8; if (rg > n_e - 1) rg = n_e - 1;
            src[i] = (const char*)act + (size_t)(off + rg) * (HH * 2) + colb;
        } else {
            int tr = (c - 32) * 8 + l8;
            src[i] = (const char*)dwb + ((size_t)e * DD + n0 + tr) * (HH * 2) + colb;
        }
    }

    f32x4 acc[8][4] = {};

#pragma unroll
    for (int i = 0; i < 8; i++) gl2lds16(src[i], lds + wvoff + i * 1024u);
    asm volatile("s_waitcnt vmcnt(0)" ::: "memory");
    __builtin_amdgcn_s_barrier();
    asm volatile("" ::: "memory");

    constexpr int NT = (HH * 2) / 128;   // 32 K-tiles
    for (int t = 0; t < NT - 1; ++t) {
        const char* La = lds + (t & 1) * 65536u;
        const char* Lb = La + 32768;
        char* nb = lds + ((t + 1) & 1) * 65536u;
        bf16x8 bfr[4];
        PHASE(0, 0, 0, t, 1);
        PHASE(1, 0, 1, t, 1);
        PHASE(0, 1, 2, t, 1);
        PHASE(1, 1, 3, t, 1);
    }
    {
        const int t = NT - 1;
        const char* La = lds + (t & 1) * 65536u;
        const char* Lb = La + 32768;
        char* nb = lds;  (void)nb;
        bf16x8 bfr[4];
        PHASE(0, 0, 0, t, 0);
        PHASE(1, 0, 1, t, 0);
        PHASE(0, 1, 2, t, 0);
        PHASE(1, 1, 3, t, 0);
    }

    // epilogue: y[grouped row] = result (f32; combine applies probs)
#pragma unroll
    for (int mi = 0; mi < 8; mi++) {
#pragma unroll
        for (int r2 = 0; r2 < 4; r2++) {
            int row = wm * 128 + mi * 16 + (lane >> 4) * 4 + r2;
            int rg = m0 + row;
            if (rg >= n_e) continue;
            size_t ybase = (size_t)(off + rg) * DD + n0 + wn * 64;
#pragma unroll
            for (int nj = 0; nj < 4; nj++)
                y[ybase + nj * 16 + l15] = acc[mi][nj][r2];
        }
    }
}

// ---------------- combine: out[t] = p0*y[slot0] + p1*y[slot1] ----------------
__global__ __launch_bounds__(256) void k_combine(
    const float* __restrict__ y,
    const int* __restrict__ slot,
    const float* __restrict__ topk_prob,
    float* __restrict__ out)
{
    int t = blockIdx.x * 2 + (threadIdx.x >> 7);
    int i = threadIdx.x & 127;
    int s0 = slot[t * 2 + 0], s1 = slot[t * 2 + 1];
    float p0 = topk_prob[t * 2 + 0], p1 = topk_prob[t * 2 + 1];
    const float4* ya = (const float4*)(y + (size_t)s0 * DD + i * 8);
    const float4* yb = (const float4*)(y + (size_t)s1 * DD + i * 8);
    float4 a0 = ya[0], a1 = ya[1], b0 = yb[0], b1 = yb[1];
    float4 o0, o1;
    o0.x = p0 * a0.x + p1 * b0.x;  o0.y = p0 * a0.y + p1 * b0.y;
    o0.z = p0 * a0.z + p1 * b0.z;  o0.w = p0 * a0.w + p1 * b0.w;
    o1.x = p0 * a1.x + p1 * b1.x;  o1.y = p0 * a1.y + p1 * b1.y;
    o1.z = p0 * a1.z + p1 * b1.z;  o1.w = p0 * a1.w + p1 * b1.w;
    float4* op = (float4*)(out + (size_t)t * DD + i * 8);
    op[0] = o0;
    op[1] = o1;
}

extern "C" void kernel_launch(void* const* d_in, const int* in_sizes, int n_in,
                              void* d_out, int out_size, void* d_ws, size_t ws_size,
                              hipStream_t stream) {
    const float* x  = (const float*)d_in[0];
    const float* rw = (const float*)d_in[1];
    const float* gw = (const float*)d_in[2];
    const float* uw = (const float*)d_in[3];
    const float* dw = (const float*)d_in[4];
    float* out = (float*)d_out;

    char* ws = (char*)d_ws;
    int*   topk_idx   = (int*)(ws + 0);
    float* topk_prob  = (float*)(ws + 65536);
    int*   counts     = (int*)(ws + 131072);
    int*   cursor     = (int*)(ws + 131104);
    int*   offsets    = (int*)(ws + 131136);
    int*   token_list = (int*)(ws + 131264);
    int*   slot       = (int*)(ws + 196800);

    unsigned short* x_bf  = (unsigned short*)(ws + 524288);
    float*          y     = (float*)(ws + 524288);   // overlays x_bf/gw_bf/uw_bf
    unsigned short* gw_bf = (unsigned short*)(ws + 17301504);
    unsigned short* uw_bf = (unsigned short*)(ws + 50855936);
    unsigned short* dw_bf = (unsigned short*)(ws + 84410368);
    unsigned short* act   = (unsigned short*)(ws + 117964800);

    hipMemsetAsync(ws + 131072, 0, 64, stream);   // counts + cursor

    k_router<<<TOK / 4, 256, 0, stream>>>(x, rw, topk_idx, topk_prob, counts, x_bf);
    k_scan<<<1, 64, 0, stream>>>(counts, offsets);
    k_scatter<<<TOK / 256, 256, 0, stream>>>(topk_idx, offsets, cursor,
                                             token_list, slot);

    k_cvt_all<<<2048, 256, 0, stream>>>(gw, uw, dw, gw_bf, uw_bf, dw_bf);

    // gateup: e = bid&7 (XCD), s = bid>>3 = n*64 + m (n-outer, m-inner)
    k_gateup_v4<<<8192, 512, 131072, stream>>>(x_bf, gw_bf, uw_bf, offsets,
                                               token_list, act);
    // down: e = bid&7, s = n*64 + m (4 n-slices)
    k_down_v4<<<2048, 512, 131072, stream>>>(act, dw_bf, offsets, y);

    k_combine<<<TOK / 2, 256, 0, stream>>>(y, slot, topk_prob, out);
}